// Round 4
// baseline (123.536 us; speedup 1.0000x reference)
//
#include <hip/hip_runtime.h>

// SparseNodeLinear: out[b,n,f] = sum_k (keep[n,k]*x[b,n,k]) * w[n,k,f] + bias[n,f]
// B=8, N=2048, K=N+1=2049, F=32. HBM-bound: w=537MB read-once dominates.
// R3: (a) each wave owns a CONTIGUOUS 512-k range -> one 256KB sequential w
// stream per wave; (b) cross-barrier w double-buffer (wvA/wvB) with raw
// s_barrier + manual lgkmcnt so 8 w-loads stay in flight across tiles.

constexpr int NB = 8;
constexpr int NN = 2048;
constexpr int NK = 2049;
constexpr int NF = 32;
constexpr size_t XSTR = (size_t)NN * NK;

using f4 = __attribute__((ext_vector_type(4))) float;

// mode: 0 = int32 mask, 1 = uint8 (numpy bool), 2 = float32
__device__ __forceinline__ float ld_scale(const void* __restrict__ mask,
                                          size_t idx, int mode) {
  bool drop;
  if (mode == 0)
    drop = ((const int*)mask)[idx] != 0;
  else if (mode == 1)
    drop = ((const unsigned char*)mask)[idx] != 0;
  else
    drop = ((const float*)mask)[idx] != 0.0f;
  return drop ? 0.0f : 1.0f;  // keep where mask==0
}

// issue 8 contiguous-run w loads for tile t into dst (8KB/wave, sequential)
#define ISSUE_W(dst, t)                                                       \
  _Pragma("unroll") for (int u = 0; u < 8; ++u) dst[u] =                      \
      __builtin_nontemporal_load(                                             \
          (const f4*)(wws + (size_t)((t)*64 + u * 8 + kk) * NF + fq * 4));

#define DO_FMA(src, cur)                                                      \
  _Pragma("unroll") for (int u = 0; u < 8; ++u) {                             \
    const int kl = ws * 64 + u * 8 + kk;                                      \
    _Pragma("unroll") for (int b = 0; b < NB; ++b) {                          \
      const float xv = xs[cur][b][kl];                                        \
      acc[b][0] = fmaf(xv, src[u][0], acc[b][0]);                             \
      acc[b][1] = fmaf(xv, src[u][1], acc[b][1]);                             \
      acc[b][2] = fmaf(xv, src[u][2], acc[b][2]);                             \
      acc[b][3] = fmaf(xv, src[u][3], acc[b][3]);                             \
    }                                                                         \
  }

// x prefetch for tile t (wave's own 64-k slice, all 8 batches)
#define X_PREFETCH(t)                                                         \
  {                                                                           \
    const size_t kg = (size_t)KW + (t)*64 + lane;                             \
    scr = ld_scale(mask, mbase + kg, mode);                                   \
    _Pragma("unroll") for (int i = 0; i < NB; ++i) xr[i] =                    \
        __builtin_nontemporal_load(&xn[(size_t)i * XSTR + kg]);               \
  }

#define X_WRITE(buf)                                                          \
  _Pragma("unroll") for (int i = 0; i < NB; ++i) xs[buf][i][ws * 64 + lane] = \
      xr[i] * scr;

#define TILE_BARRIER()                                  \
  asm volatile("s_waitcnt lgkmcnt(0)" ::: "memory");    \
  __builtin_amdgcn_s_barrier();                         \
  __builtin_amdgcn_sched_barrier(0);

__global__ __launch_bounds__(256) void snl_kernel(
    const float* __restrict__ x, const float* __restrict__ w,
    const float* __restrict__ bias, const void* __restrict__ mask,
    float* __restrict__ out) {
  __shared__ float xs[2][NB][256];  // double-buffered pre-masked x (16KB)
  __shared__ float part[4][8][32];
  __shared__ int smode;

  const int tid = threadIdx.x;
  const int n = blockIdx.x;

  // --- mask dtype sniff ---
  if (tid < 64) {
    unsigned v = ((const unsigned*)mask)[tid];
    unsigned long long bf = __ballot((v >> 24) == 0x3Fu);
    unsigned long long bg = __ballot(v > 1u);
    if (tid == 0) smode = bf ? 2 : (bg ? 1 : 0);
  }
  __syncthreads();
  const int mode = smode;

  const int fq = tid & 7;         // f-quad
  const int kk = (tid >> 3) & 7;  // k within 8-slice
  const int ws = tid >> 6;        // wave id
  const int lane = tid & 63;
  const int KW = ws * 512;        // wave's contiguous k-range base

  const float* xn = x + (size_t)n * NK;
  const float* wrow = w + (size_t)n * NK * NF;
  const float* wws = wrow + (size_t)KW * NF;  // wave's 256KB w stream base
  const size_t mbase = (size_t)n * NK;

  float acc[NB][4];
#pragma unroll
  for (int b = 0; b < NB; ++b)
#pragma unroll
    for (int j = 0; j < 4; ++j) acc[b][j] = 0.0f;

  f4 wvA[8], wvB[8];
  float xr[NB], scr;

  // prologue: w tile 0 in flight + x tile 0 staged
  ISSUE_W(wvA, 0);
  X_PREFETCH(0);
  X_WRITE(0);
  TILE_BARRIER();

  for (int t = 0; t < 8; t += 2) {
    // ---- even tile t: consume wvA/xs[0]; prefetch tile t+1 ----
    ISSUE_W(wvB, t + 1);
    X_PREFETCH(t + 1);
    DO_FMA(wvA, 0);
    X_WRITE(1);
    TILE_BARRIER();
    // ---- odd tile t+1: consume wvB/xs[1]; prefetch tile t+2 ----
    if (t + 2 < 8) {
      ISSUE_W(wvA, t + 2);
      X_PREFETCH(t + 2);
      DO_FMA(wvB, 1);
      X_WRITE(0);
      TILE_BARRIER();
    } else {
      DO_FMA(wvB, 1);
    }
  }

  // --- reduce over kk bits (lane bits 3..5), then cross-wave ---
#pragma unroll
  for (int m = 8; m <= 32; m <<= 1) {
#pragma unroll
    for (int b = 0; b < NB; ++b)
#pragma unroll
      for (int j = 0; j < 4; ++j)
        acc[b][j] += __shfl_xor(acc[b][j], m, 64);
  }
  __syncthreads();  // xs no longer needed; part[] writes follow
  if (lane < 8) {
#pragma unroll
    for (int b = 0; b < NB; ++b)
#pragma unroll
      for (int j = 0; j < 4; ++j) part[ws][fq][b * 4 + j] = acc[b][j];
  }
  __syncthreads();

  if (tid < 64) {
    const int b = tid >> 3;
    const int f2 = tid & 7;
    f4 o = *(const f4*)(bias + (size_t)n * NF + f2 * 4);
    // k=2048 tail (K = 4*512 + 1)
    {
      const float sc = ld_scale(mask, mbase + 2048, mode);
      const float xv = xn[(size_t)b * XSTR + 2048] * sc;
      const f4 wv = *(const f4*)(wrow + (size_t)2048 * NF + f2 * 4);
      o += xv * wv;
    }
#pragma unroll
    for (int wsi = 0; wsi < 4; ++wsi) {
      const f4 p = *(const f4*)&part[wsi][f2][b * 4];
      o += p;
    }
    *(f4*)(out + ((size_t)b * NN + n) * NF + f2 * 4) = o;
  }
}

extern "C" void kernel_launch(void* const* d_in, const int* in_sizes, int n_in,
                              void* d_out, int out_size, void* d_ws,
                              size_t ws_size, hipStream_t stream) {
  const float* x = (const float*)d_in[0];
  const float* w = (const float*)d_in[1];
  const float* bias = (const float*)d_in[2];
  const void* mask = d_in[3];  // dtype sniffed on device
  float* out = (float*)d_out;

  hipLaunchKernelGGL(snl_kernel, dim3(NN), dim3(256), 0, stream, x, w, bias,
                     mask, out);
}

// Round 6
// 121.915 us; speedup vs baseline: 1.0133x; 1.0133x over previous
//
#include <hip/hip_runtime.h>

// SparseNodeLinear: out[b,n,f] = sum_k (keep[n,k]*x[b,n,k]) * w[n,k,f] + bias[n,f]
// B=8, N=2048, K=N+1=2049, F=32. HBM-bound: w=537MB read-once dominates.
// R5 = resubmit of R4 (container died before benching it).
// R4 = R2 (best, 121.9us) + permuted xs layout so the inner loop reads x via
// ds_read_b128 (16/tile) instead of ds_read_b32 (64/tile). Global traffic
// byte-identical to R2. R3's w-dbuf/raw-barrier reverted (regressed).

constexpr int NB = 8;
constexpr int NN = 2048;
constexpr int NK = 2049;
constexpr int NF = 32;
constexpr int BK = 256;
constexpr int NTL = 8;  // 8*256 = 2048, k=2048 tail in epilogue
constexpr int XPAD = 264;  // padded xs row (floats): breaks b-row bank overlap
constexpr size_t XSTR = (size_t)NN * NK;

using f4 = __attribute__((ext_vector_type(4))) float;

// mode: 0 = int32 mask, 1 = uint8 (numpy bool), 2 = float32
__device__ __forceinline__ float ld_scale(const void* __restrict__ mask,
                                          size_t idx, int mode) {
  bool drop;
  if (mode == 0)
    drop = ((const int*)mask)[idx] != 0;
  else if (mode == 1)
    drop = ((const unsigned char*)mask)[idx] != 0;
  else
    drop = ((const float*)mask)[idx] != 0.0f;
  return drop ? 0.0f : 1.0f;  // keep where mask==0
}

__global__ __launch_bounds__(256) void snl_kernel(
    const float* __restrict__ x, const float* __restrict__ w,
    const float* __restrict__ bias, const void* __restrict__ mask,
    float* __restrict__ out) {
  __shared__ float xs[2][NB][XPAD];  // double-buffered pre-masked x (~16.9KB)
  __shared__ float part[4][8][32];
  __shared__ int smode;

  const int tid = threadIdx.x;
  const int n = blockIdx.x;

  // --- mask dtype sniff ---
  if (tid < 64) {
    unsigned v = ((const unsigned*)mask)[tid];
    unsigned long long bf = __ballot((v >> 24) == 0x3Fu);
    unsigned long long bg = __ballot(v > 1u);
    if (tid == 0) smode = bf ? 2 : (bg ? 1 : 0);
  }
  __syncthreads();
  const int mode = smode;

  const int fq = tid & 7;         // f-quad
  const int kk = (tid >> 3) & 7;  // k within 8-wide slice
  const int ws = tid >> 6;        // wave id
  const int lane = tid & 63;

  // stage: thread owns k_local = tid, writes to permuted slot
  // p(k) = (k>>6)*64 + (k&7)*8 + ((k>>3)&7)  -> [ws_k][kk][u]
  const int p_stage = ws * 64 + (lane & 7) * 8 + (lane >> 3);
  // compute: thread reads p = ws*64 + kk*8 + u, u contiguous -> b128
  const int p_read = ws * 64 + kk * 8;

  const float* xn = x + (size_t)n * NK;
  const float* wrow = w + (size_t)n * NK * NF;
  const size_t mbase = (size_t)n * NK;

  float acc[NB][4];
#pragma unroll
  for (int b = 0; b < NB; ++b)
#pragma unroll
    for (int j = 0; j < 4; ++j) acc[b][j] = 0.0f;

  // prologue: stage tile 0 (global pattern identical to R2)
  {
    const float sc = ld_scale(mask, mbase + tid, mode);
#pragma unroll
    for (int i = 0; i < NB; ++i)
      xs[0][i][p_stage] =
          __builtin_nontemporal_load(&xn[(size_t)i * XSTR + tid]) * sc;
  }
  __syncthreads();

  for (int t = 0; t < NTL; ++t) {
    const int cur = t & 1;
    const bool pf = (t + 1 < NTL);
    float xr[NB], scr = 0.0f;
    if (pf) {  // issue next-tile x loads early
      const int kg = (t + 1) * BK + tid;
      scr = ld_scale(mask, mbase + kg, mode);
#pragma unroll
      for (int i = 0; i < NB; ++i)
        xr[i] = __builtin_nontemporal_load(&xn[(size_t)i * XSTR + kg]);
    }

    // wave ws streams 8KB contiguous: k = t*256 + ws*64 + u*8 + kk
    const float* wt = wrow + (size_t)t * BK * NF + (size_t)ws * 64 * NF;
    f4 wv[8];
#pragma unroll
    for (int u = 0; u < 8; ++u)
      wv[u] = __builtin_nontemporal_load(
          (const f4*)(wt + (size_t)(u * 8 + kk) * NF + fq * 4));

#pragma unroll
    for (int b = 0; b < NB; ++b) {
#pragma unroll
      for (int q = 0; q < 2; ++q) {
        const f4 xv = *(const f4*)&xs[cur][b][p_read + q * 4];  // ds_read_b128
#pragma unroll
        for (int j = 0; j < 4; ++j) {
          const int u = q * 4 + j;
          acc[b][0] = fmaf(xv[j], wv[u][0], acc[b][0]);
          acc[b][1] = fmaf(xv[j], wv[u][1], acc[b][1]);
          acc[b][2] = fmaf(xv[j], wv[u][2], acc[b][2]);
          acc[b][3] = fmaf(xv[j], wv[u][3], acc[b][3]);
        }
      }
    }

    if (pf) {  // write staged tile after compute
#pragma unroll
      for (int i = 0; i < NB; ++i) xs[cur ^ 1][i][p_stage] = xr[i] * scr;
    }
    __syncthreads();
  }

  // --- reduce over kk bits (lane bits 3..5), then cross-wave ---
#pragma unroll
  for (int m = 8; m <= 32; m <<= 1) {
#pragma unroll
    for (int b = 0; b < NB; ++b)
#pragma unroll
      for (int j = 0; j < 4; ++j)
        acc[b][j] += __shfl_xor(acc[b][j], m, 64);
  }
  if (lane < 8) {
#pragma unroll
    for (int b = 0; b < NB; ++b)
#pragma unroll
      for (int j = 0; j < 4; ++j) part[ws][fq][b * 4 + j] = acc[b][j];
  }
  __syncthreads();

  if (tid < 64) {
    const int b = tid >> 3;
    const int f2 = tid & 7;
    f4 o = *(const f4*)(bias + (size_t)n * NF + f2 * 4);
    // k=2048 tail (K = 8*256 + 1)
    {
      const float sc = ld_scale(mask, mbase + 2048, mode);
      const float xv = xn[(size_t)b * XSTR + 2048] * sc;
      const f4 wv = *(const f4*)(wrow + (size_t)2048 * NF + f2 * 4);
      o += xv * wv;
    }
#pragma unroll
    for (int wsi = 0; wsi < 4; ++wsi) {
      const f4 p = *(const f4*)&part[wsi][f2][b * 4];
      o += p;
    }
    *(f4*)(out + ((size_t)b * NN + n) * NF + f2 * 4) = o;
  }
}

extern "C" void kernel_launch(void* const* d_in, const int* in_sizes, int n_in,
                              void* d_out, int out_size, void* d_ws,
                              size_t ws_size, hipStream_t stream) {
  const float* x = (const float*)d_in[0];
  const float* w = (const float*)d_in[1];
  const float* bias = (const float*)d_in[2];
  const void* mask = d_in[3];  // dtype sniffed on device
  float* out = (float*)d_out;

  hipLaunchKernelGGL(snl_kernel, dim3(NN), dim3(256), 0, stream, x, w, bias,
                     mask, out);
}